// Round 5
// baseline (463.100 us; speedup 1.0000x reference)
//
#include <hip/hip_runtime.h>
#include <math.h>

#define B 8
#define C 512
#define K 19
#define HW 16384
#define ROWS (B * K)             // 152
#define L2E 1.44269504088896340736f

// gather config — R5: occupancy experiment. CPW 4->2 halves acc VGPRs so the
// allocator can fit 6 waves/SIMD (24 waves/CU, +50% vs every prior round's 16).
#define NW 8                     // waves per block (512 threads)
#define CPW 2                    // c-rows per wave -> acc[2][19] = 38 VGPRs
#define CPB (CPW * NW)           // 16 c-rows per block (same as R4)
#define CG (C / CPB)             // 32 c-groups
#define NSC 4                    // grid = 8*32*4 = 1024 blocks (512-thr)
#define SCHUNK (HW / NSC)        // 4096 s per block
#define TS 256                   // s-tile staged in LDS
#define NT (SCHUNK / TS)         // 16 tiles per block
#define TILE_F (K * TS)          // 4864 floats = 19,456 B per probs tile

typedef __attribute__((address_space(3))) unsigned int lds_u32;
typedef const __attribute__((address_space(1))) unsigned int glb_u32;

// Pass 1: row softmax -> probs in TILE-CONTIGUOUS layout probs[b][sc][t][k][TS]
// (unchanged from R4). Blocks 0..18 also zero `out`, replacing the memset.
__global__ __launch_bounds__(1024)
void probs_kernel(const float* __restrict__ aux, float* __restrict__ probs,
                  float* __restrict__ out) {
    int row  = blockIdx.x;                 // 0..151 = b*K + k
    int tid  = threadIdx.x;                // 0..1023
    int lane = tid & 63;
    int wave = tid >> 6;                   // == tile index t of this thread's s-range
    __shared__ float red[16];

    if (row < 19)
        ((float4*)out)[(size_t)row * 1024 + tid] = make_float4(0.f, 0.f, 0.f, 0.f);

    const float4* x4 = (const float4*)(aux + (size_t)row * HW);

    float4 v[4];
    #pragma unroll
    for (int i = 0; i < 4; i++) v[i] = x4[tid + i * 1024];   // i == sc

    float m = -INFINITY;
    #pragma unroll
    for (int i = 0; i < 4; i++)
        m = fmaxf(m, fmaxf(fmaxf(v[i].x, v[i].y), fmaxf(v[i].z, v[i].w)));
    #pragma unroll
    for (int off = 32; off > 0; off >>= 1) m = fmaxf(m, __shfl_xor(m, off, 64));
    if (lane == 0) red[wave] = m;
    __syncthreads();
    #pragma unroll
    for (int w = 0; w < 16; w++) m = fmaxf(m, red[w]);
    __syncthreads();

    float nm = -m * L2E;
    float s = 0.f;
    #pragma unroll
    for (int i = 0; i < 4; i++) {
        v[i].x = exp2f(fmaf(v[i].x, L2E, nm));
        v[i].y = exp2f(fmaf(v[i].y, L2E, nm));
        v[i].z = exp2f(fmaf(v[i].z, L2E, nm));
        v[i].w = exp2f(fmaf(v[i].w, L2E, nm));
        s += (v[i].x + v[i].y) + (v[i].z + v[i].w);
    }
    #pragma unroll
    for (int off = 32; off > 0; off >>= 1) s += __shfl_xor(s, off, 64);
    if (lane == 0) red[wave] = s;
    __syncthreads();
    float Z = 0.f;
    #pragma unroll
    for (int w = 0; w < 16; w++) Z += red[w];
    float inv = 1.0f / Z;

    int b = row / K, k = row - b * K;
    float4* dst4 = (float4*)probs;
    #pragma unroll
    for (int i = 0; i < 4; i++) {
        float4 o;
        o.x = v[i].x * inv; o.y = v[i].y * inv;
        o.z = v[i].z * inv; o.w = v[i].w * inv;
        size_t idx = ((((size_t)(b * NSC + i) * NT + wave) * K + k) << 6) + lane;
        dst4[idx] = o;
    }
}

// Gather — R4 skeleton (counted-vmcnt raw barriers, 2-deep feats ping-pong,
// tile-contiguous probs staging, XCD swizzle, rotation, setprio) at HIGHER
// OCCUPANCY: 512-thr blocks, CPW=2.
//
// ALLOCATOR LAW (R1-R5 of prior session, measured): VGPR budget =
// 512/(2*declared_min_waves_per_eu). wpe(2)->128, wpe(4)->64 (catastrophic
// spill at acc[4][19]). Here: wpe(3) -> budget ~85; live set ~55-65
// (acc 38 + fA/fB 16 + addressing) -> fits, no spill, and VGPR<=85 gives
// 6 waves/SIMD = 24 resident waves/CU (3 of the 4 LDS-capable blocks
// resident, 4th backfills). Every prior round ran 16 waves/CU.
// WAITB keep = 2 (= feats loads per FLOAD, the newest entries in the
// per-wave vmcnt FIFO; gll count per wave is 2-3, all retired by keep=2).
__global__ __launch_bounds__(512)
__attribute__((amdgpu_waves_per_eu(3)))
void gather_kernel(const float* __restrict__ feats, const float* __restrict__ probs,
                   float* __restrict__ out) {
    __shared__ __align__(16) float plds[2][K][TS];   // 38,912 B

    int bid = blockIdx.x;                  // 0..1023
    int xcd = bid & 7;
    int lid = xcd * 128 + (bid >> 3);      // XCD-contiguous remap
    int cg  = lid & (CG - 1);
    int grp = lid >> 5;                    // b*NSC + sc
    int sc  = grp & (NSC - 1);
    int b   = grp >> 2;
    int rot = (bid * 11) & (NT - 1);       // per-block tile-phase rotation

    int tid  = threadIdx.x;
    int lane = tid & 63;
    int wave = tid >> 6;                   // 0..7
    int c0   = cg * CPB + wave * CPW;

    const float* Pbase = probs + (size_t)(b * NSC + sc) * (NT * TILE_F);
    const float* Fbase = feats + ((size_t)b * C + c0) * HW + sc * SCHUNK + lane * 4;

    float acc[CPW][K];
    #pragma unroll
    for (int c = 0; c < CPW; c++)
        #pragma unroll
        for (int k = 0; k < K; k++) acc[c][k] = 0.f;

    float4 fA[CPW], fB[CPW];

#define SROT(t) (((t) + rot) & (NT - 1))
#define STAGE(bi, t) do { \
    const float* pt_ = Pbase + (size_t)SROT(t) * TILE_F; \
    for (int i = wave; i < K; i += NW) \
        __builtin_amdgcn_global_load_lds((glb_u32*)(pt_ + i * TS + lane * 4), \
                                         (lds_u32*)(&plds[bi][0][0] + i * TS), 16, 0, 0); \
    __builtin_amdgcn_sched_barrier(0); } while (0)
#define FLOAD(fa, t) do { int s_ = SROT(t) * TS; \
    _Pragma("unroll") for (int c = 0; c < CPW; c++) \
        fa[c] = *(const float4*)(Fbase + (size_t)c * HW + s_); } while (0)
#define FMATILE(bi, fa) do { \
    __builtin_amdgcn_s_setprio(1); \
    _Pragma("unroll") for (int k = 0; k < K; k++) { \
        float4 pv = *(const float4*)(&plds[bi][k][lane * 4]); \
        _Pragma("unroll") for (int c = 0; c < CPW; c++) { \
            acc[c][k] = fmaf(pv.x, fa[c].x, acc[c][k]); \
            acc[c][k] = fmaf(pv.y, fa[c].y, acc[c][k]); \
            acc[c][k] = fmaf(pv.z, fa[c].z, acc[c][k]); \
            acc[c][k] = fmaf(pv.w, fa[c].w, acc[c][k]); } } \
    __builtin_amdgcn_s_setprio(0); } while (0)
#define WAITB(keep) do { \
    asm volatile("s_waitcnt vmcnt(" #keep ")" ::: "memory"); \
    __builtin_amdgcn_sched_barrier(0); \
    __builtin_amdgcn_s_barrier(); \
    __builtin_amdgcn_sched_barrier(0); } while (0)

    // prologue: probs(0)->buf0, feats(0)->fA, feats(1)->fB
    STAGE(0, 0);
    FLOAD(fA, 0);
    FLOAD(fB, 1);

    // steady state, 2-tile unrolled pairs: tiles 0..13
    #pragma unroll 1
    for (int tp = 0; tp < 7; ++tp) {
        int t = tp * 2;
        WAITB(2);                 // gll(t)+old feats done; 2 newest feats in flight
        STAGE(1, t + 1);
        FMATILE(0, fA);
        FLOAD(fA, t + 2);         // used 2 tiles later
        WAITB(2);
        STAGE(0, t + 2);
        FMATILE(1, fB);
        FLOAD(fB, t + 3);
    }
    // tile 14
    WAITB(2);
    STAGE(1, 15);
    FMATILE(0, fA);
    // tile 15 (epilogue: full drain once)
    WAITB(0);
    FMATILE(1, fB);

#undef SROT
#undef STAGE
#undef FLOAD
#undef FMATILE
#undef WAITB

    // butterfly reduce over 64 lanes, then one atomic per (c,k) per block
    #pragma unroll
    for (int c = 0; c < CPW; c++)
        #pragma unroll
        for (int k = 0; k < K; k++) {
            float v = acc[c][k];
            #pragma unroll
            for (int off = 32; off > 0; off >>= 1) v += __shfl_xor(v, off, 64);
            if (lane == 0)
                atomicAdd(&out[((size_t)b * C + c0 + c) * K + k], v);
        }
}

extern "C" void kernel_launch(void* const* d_in, const int* in_sizes, int n_in,
                              void* d_out, int out_size, void* d_ws, size_t ws_size,
                              hipStream_t stream) {
    const float* feats = (const float*)d_in[0];   // bb_feats [8,512,128,128]
    const float* aux   = (const float*)d_in[1];   // aux_out  [8,19,128,128]
    float* out   = (float*)d_out;                 // [8,512,19,1]
    float* probs = (float*)d_ws;                  // tiled [8][4][16][19][256] = 10 MB

    probs_kernel<<<ROWS, 1024, 0, stream>>>(aux, probs, out);
    gather_kernel<<<B * CG * NSC, 512, 0, stream>>>(feats, probs, out);
}